// Round 5
// baseline (118977.161 us; speedup 1.0000x reference)
//
#include <hip/hip_runtime.h>
#include <hip/hip_bf16.h>

// NeuralODE: B=256, Z=1024, H=2048, T=128, explicit Euler, 127 steps.
// Round 9: R8's L2-resident sync fabric with the poll comparator fixed.
//  - R8's == rendezvous permanently desyncs after one transient guard trip
//    (every wait then burns the full guard for all 127 steps -> 17ms).
//    Polls are back to >= (monotone flags; interlock bounds lead to one
//    phase, so >= admits no unsafe early pass within a launch).
//  - Cross-launch stale-flag protection is structural now: zero_flags runs
//    as 256 blocks mirroring ode_main's grid; block b plain-stores 0 into
//    the slot ode_main block b owns -> the zero lands in the SAME XCD L2
//    that could hold a stale dirty line, overwriting it in place. Safe
//    under WB+INV / WB-only / no dispatch-boundary cache maintenance.
//  - Data publishes (fast): plain stores into shared XCD L2, drained by
//    __syncthreads' vmcnt(0). Flag stores: plain. Flag polls + staging
//    loads: sc0 (L1-bypass, L2-read). Slow path: bit-exact R4 sc1.
//  - All polls bounded (guard 4096): failures surface as passed:false,
//    never a hung container.

#define ZD 1024
#define HD 2048
#define TT 128
#define BB 256
#define ZT (ZD * TT)
#define POLL_GUARD 4096
#define HSK_GUARD 4096

typedef __attribute__((ext_vector_type(8))) short bfrag;  // 8 bf16
typedef __attribute__((ext_vector_type(4))) float ffrag;  // 4 fp32
typedef unsigned long long ull;

__device__ short g_W1b[HD * ZD];       // 4 MB bf16, [h][z]
__device__ short g_W2b[ZD * HD];       // 4 MB bf16, [z][h]
__device__ ull g_zbx[BB * ZD / 4];     // bf16 z exchange, 8B chunks
__device__ ull g_hbx[BB * HD / 4];     // bf16 h exchange, 8B chunks
__device__ unsigned g_zfl[16 * 16 * 32];  // per-(mg,ng) z flag, 128B padded
__device__ unsigned g_hfl[16 * 16 * 32];  // per-(mg,ng) h flag, 128B padded
__device__ unsigned g_xcc[BB];            // per-block physical XCD id

__device__ __forceinline__ short f2bf(float f) {
  union { float f; unsigned u; } x; x.f = f;
  unsigned r = x.u + 0x7fffu + ((x.u >> 16) & 1u);  // RNE
  return (short)(r >> 16);
}

// XOR-swizzle of 16B blocks within an LDS row (kills stride bank conflicts).
__device__ __forceinline__ int swzA(int row, int k) {  // 1024-wide rows
  return (row << 10) + ((((k >> 3) ^ row) << 3) | (k & 7));
}
__device__ __forceinline__ int swzH(int row, int k) {  // 2048-wide rows
  return (row << 11) + ((((k >> 3) ^ row) << 3) | (k & 7));
}

// 8B load that bypasses L1 and reads the (XCD-shared) L2.
__device__ __forceinline__ ull ld_sc0_b64(const ull* p) {
  ull v;
  asm volatile("global_load_dwordx2 %0, %1, off sc0" : "=v"(v) : "v"(p));
  return v;  // caller must s_waitcnt vmcnt(0) before use
}

// 4B flag poll: L1-bypass read of the shared XCD L2.
__device__ __forceinline__ unsigned ld_sc0_b32(const unsigned* p) {
  unsigned v;
  asm volatile("global_load_dword %0, %1, off sc0\n\ts_waitcnt vmcnt(0)"
               : "=v"(v) : "v"(p) : "memory");
  return v;
}

__global__ void zero_flags_kernel() {
  // 256 blocks, mirroring ode_main's grid: block b zeroes the slot that
  // ode_main block b owns, with a PLAIN store -> lands in the same XCD L2
  // that could hold a stale dirty flag line from a previous launch.
  const int b = blockIdx.x;
  if (threadIdx.x == 0) {
    const int kb = b >> 3;
    const int mg = ((b & 7) << 1) | (kb >> 4);
    const int ng = kb & 15;
    const int slot = ((mg << 4) + ng) << 5;
    *(volatile unsigned*)&g_zfl[slot] = 0u;
    *(volatile unsigned*)&g_hfl[slot] = 0u;
    __hip_atomic_store(&g_xcc[b], 0xFFFFFFFFu, __ATOMIC_RELAXED,
                       __HIP_MEMORY_SCOPE_AGENT);
  }
}

__global__ void cvt_weights_kernel(const float* __restrict__ W1,
                                   const float* __restrict__ W2) {
  const int i = (blockIdx.x * 256 + threadIdx.x) << 2;
  {
    const float4 v = *(const float4*)(W1 + i);
    short4 o; o.x = f2bf(v.x); o.y = f2bf(v.y); o.z = f2bf(v.z); o.w = f2bf(v.w);
    *(short4*)(g_W1b + i) = o;
  }
  {
    const float4 v = *(const float4*)(W2 + i);
    short4 o; o.x = f2bf(v.x); o.y = f2bf(v.y); o.z = f2bf(v.z); o.w = f2bf(v.w);
    *(short4*)(g_W2b + i) = o;
  }
}

__global__ __launch_bounds__(512, 2) void ode_main(
    const float* __restrict__ z0, const float* __restrict__ ts,
    const float* __restrict__ wt, const float* __restrict__ b1,
    const float* __restrict__ b2, float* __restrict__ out) {
  __shared__ short buf[32 * 1024];        // 64 KB, time-shared
  short* const hloc = buf + 16384;        // 16 rows x stride 132 (after GEMM1)
  short* const zloc = buf + 8192;         // 16 rows x stride 68 (after GEMM2)
  float* const red = (float*)buf;         // 4 KB K-split reduction (after GEMM2)

  const int tid = threadIdx.x;
  const int wv = tid >> 6, lane = tid & 63, l16 = lane & 15, quad = lane >> 4;
  const int b = blockIdx.x;
  // XCD-local grouping: members of a row-group share bid&7 -> same XCD
  // (verified below; falls back to sc1 protocol if the mapping doesn't hold).
  const int kb = b >> 3;                        // 0..31 within presumed XCD
  const int mg = ((b & 7) << 1) | (kb >> 4);    // row group, XCD-local
  const int ng = kb & 15;                       // column slice within group
  const int r0 = mg << 4;
  const int nq = wv & 3, kh = wv >> 2;
  const int zc0 = (ng << 6) + (nq << 4);
  const int myslot = ((mg << 4) + ng) << 5;        // my padded flag index
  const int pollslot = ((mg << 4) + l16) << 5;     // wave-0 poll index

  // ---- XCD identity handshake: decide fast (L2-local) vs slow (sc1) ----
  __shared__ unsigned s_x[24];
  __shared__ int s_fastsh;
  {
    const unsigned xcc = (unsigned)__builtin_amdgcn_s_getreg(6164) & 7u;
    // 6164 = hwreg(id=20 /*HW_REG_XCC_ID*/, offset=0, size=4)
    if (tid == 0)
      __hip_atomic_store(&g_xcc[b], xcc, __ATOMIC_RELAXED,
                         __HIP_MEMORY_SCOPE_AGENT);
    if (wv == 0) {
      int src = 0;
      if (lane < 16) {
        // bid of member `lane` of my group
        src = (mg >> 1) + ((((mg & 1) << 4) + lane) << 3);
      } else if (lane < 24) {
        src = lane - 16;  // first octet, for distinctness sanity check
      }
      unsigned v = 0xFFFFFFFFu;
      int guard = 0;
      while (true) {
        if (lane < 24 && v == 0xFFFFFFFFu)
          v = __hip_atomic_load(&g_xcc[src], __ATOMIC_RELAXED,
                                __HIP_MEMORY_SCOPE_AGENT);
        if (__all(lane >= 24 || v != 0xFFFFFFFFu)) break;
        if (++guard > HSK_GUARD) break;  // -> slow path
        __builtin_amdgcn_s_sleep(2);
      }
      if (lane < 24) s_x[lane] = v;
    }
    __syncthreads();
    if (tid == 0) {
      int ok = 1;
      const unsigned v0 = s_x[0];
      ok &= (v0 != 0xFFFFFFFFu);
      for (int j = 1; j < 16; ++j) ok &= (s_x[j] == v0);   // group co-located
      unsigned msk = 0;
      for (int j = 16; j < 24; ++j) msk |= 1u << (s_x[j] & 7u);
      ok &= (msk == 0xFFu);  // 8 distinct XCDs in first octet (hwreg sanity)
      s_fastsh = ok;
    }
    __syncthreads();
  }
  const int fast = s_fastsh;

  float zreg[4];  // fp32 z state, valid in kh==0 waves

  // ---- init: z0 -> registers, out[t=0], publish bf16 z(0) ----
  if (kh == 0) {
#pragma unroll
    for (int rg = 0; rg < 4; ++rg) {
      const int row = (quad << 2) + rg;
      zreg[rg] = z0[(r0 + row) * ZD + zc0 + l16];
      out[(size_t)(r0 + row) * ZT + (size_t)(zc0 + l16) * TT] = zreg[rg];
      zloc[row * 68 + (nq << 4) + l16] = f2bf(zreg[rg]);
    }
  }
  __syncthreads();
  if (tid < 256) {
    const int row = tid >> 4, ch = (tid & 15) << 2;
    const ull v = *(const ull*)(zloc + row * 68 + ch);
    ull* const p = &g_zbx[((r0 + row) * ZD + (ng << 6) + ch) >> 2];
    if (fast) *(volatile ull*)p = v;
    else __hip_atomic_store(p, v, __ATOMIC_RELAXED, __HIP_MEMORY_SCOPE_AGENT);
  }
  __syncthreads();  // vmcnt(0): z(0) at coherence point (XCD L2 if fast)
  if (tid == 0) {
    if (fast) *(volatile unsigned*)&g_zfl[myslot] = 1u;
    else __hip_atomic_store(&g_zfl[myslot], 1u, __ATOMIC_RELAXED,
                            __HIP_MEMORY_SCOPE_AGENT);
  }

#pragma unroll 1
  for (int t = 0; t < TT - 1; ++t) {
    const float tv = ts[t];
    const float dtv = ts[t + 1] - tv;

    // ---- wait: z(t) published by all 16 group members ----
    if (wv == 0) {
      const unsigned tgt = (unsigned)(t + 1);
      int guard = 0;
      if (fast) {
        while (true) {
          const unsigned f = ld_sc0_b32(&g_zfl[pollslot]);
          if (__all(f >= tgt)) break;      // monotone flags: >= self-heals
          if (++guard > POLL_GUARD) break; // hang-proof
          __builtin_amdgcn_s_sleep(1);
        }
      } else {
        while (true) {
          const unsigned f = __hip_atomic_load(
              &g_zfl[pollslot], __ATOMIC_RELAXED, __HIP_MEMORY_SCOPE_AGENT);
          if (__all(f >= tgt)) break;
          if (++guard > POLL_GUARD) break;
          __builtin_amdgcn_s_sleep(2);
        }
      }
    }
    __syncthreads();

    // ---- stage z (16x1024 bf16) into LDS, swizzled ----
    if (fast) {
      ull vz[8];
#pragma unroll
      for (int i = 0; i < 8; ++i) {
        const int e = tid + (i << 9);
        const int r = e >> 8, kz = (e & 255) << 2;
        vz[i] = ld_sc0_b64(&g_zbx[((r0 + r) * ZD + kz) >> 2]);
      }
      asm volatile("s_waitcnt vmcnt(0)" ::: "memory");
#pragma unroll
      for (int i = 0; i < 8; ++i) {
        const int e = tid + (i << 9);
        const int r = e >> 8, kz = (e & 255) << 2;
        *(ull*)(buf + swzA(r, kz)) = vz[i];
      }
    } else {
#pragma unroll
      for (int i = 0; i < 8; ++i) {
        const int e = tid + (i << 9);
        const int r = e >> 8, kz = (e & 255) << 2;
        const ull v = __hip_atomic_load(&g_zbx[((r0 + r) * ZD + kz) >> 2],
                                        __ATOMIC_RELAXED,
                                        __HIP_MEMORY_SCOPE_AGENT);
        *(ull*)(buf + swzA(r, kz)) = v;
      }
    }
    __syncthreads();

    // ---- GEMM1: h rows [r0,+16) cols [hc0,+16), K=1024 ----
    const int hc0 = (ng << 7) + (wv << 4);
    ffrag accA = {0.f, 0.f, 0.f, 0.f};
#pragma unroll 8
    for (int kk = 0; kk < 32; ++kk) {
      const int k0 = (kk << 5) + (quad << 3);
      const bfrag a = *(const bfrag*)(buf + swzA(l16, k0));
      const bfrag bm = *(const bfrag*)(g_W1b + (size_t)(hc0 + l16) * ZD + k0);
      accA = __builtin_amdgcn_mfma_f32_16x16x32_bf16(a, bm, accA, 0, 0, 0);
    }
    {
      const int hc = hc0 + l16;
      const float wtv = wt[hc], b1v = b1[hc];
      const int cl = (wv << 4) + l16;
#pragma unroll
      for (int rg = 0; rg < 4; ++rg)
        hloc[((quad << 2) + rg) * 132 + cl] =
            f2bf(tanhf(accA[rg] + tv * wtv + b1v));
    }
    __syncthreads();

    // ---- publish h slice (16x128) as 8B chunks ----
    {
      const int row = tid >> 5, ch = (tid & 31) << 2;
      const ull v = *(const ull*)(hloc + row * 132 + ch);
      ull* const p = &g_hbx[((r0 + row) * HD + (ng << 7) + ch) >> 2];
      if (fast) *(volatile ull*)p = v;
      else __hip_atomic_store(p, v, __ATOMIC_RELAXED, __HIP_MEMORY_SCOPE_AGENT);
    }
    __syncthreads();  // vmcnt(0): h(t) at coherence point
    if (tid == 0) {
      if (fast) *(volatile unsigned*)&g_hfl[myslot] = (unsigned)(t + 1);
      else __hip_atomic_store(&g_hfl[myslot], (unsigned)(t + 1),
                              __ATOMIC_RELAXED, __HIP_MEMORY_SCOPE_AGENT);
    }

    // ---- wait: h(t) published by all 16 group members ----
    if (wv == 0) {
      const unsigned tgt = (unsigned)(t + 1);
      int guard = 0;
      if (fast) {
        while (true) {
          const unsigned f = ld_sc0_b32(&g_hfl[pollslot]);
          if (__all(f >= tgt)) break;
          if (++guard > POLL_GUARD) break;
          __builtin_amdgcn_s_sleep(1);
        }
      } else {
        while (true) {
          const unsigned f = __hip_atomic_load(
              &g_hfl[pollslot], __ATOMIC_RELAXED, __HIP_MEMORY_SCOPE_AGENT);
          if (__all(f >= tgt)) break;
          if (++guard > POLL_GUARD) break;
          __builtin_amdgcn_s_sleep(2);
        }
      }
    }
    __syncthreads();

    // ---- stage h (16x2048 bf16 = 64 KB) into LDS, swizzled ----
    if (fast) {
      ull vh[16];
#pragma unroll
      for (int i = 0; i < 16; ++i) {
        const int e = tid + (i << 9);
        const int r = e >> 9, kx = (e & 511) << 2;
        vh[i] = ld_sc0_b64(&g_hbx[((r0 + r) * HD + kx) >> 2]);
      }
      asm volatile("s_waitcnt vmcnt(0)" ::: "memory");
#pragma unroll
      for (int i = 0; i < 16; ++i) {
        const int e = tid + (i << 9);
        const int r = e >> 9, kx = (e & 511) << 2;
        *(ull*)(buf + swzH(r, kx)) = vh[i];
      }
    } else {
#pragma unroll
      for (int i = 0; i < 16; ++i) {
        const int e = tid + (i << 9);
        const int r = e >> 9, kx = (e & 511) << 2;
        const ull v = __hip_atomic_load(&g_hbx[((r0 + r) * HD + kx) >> 2],
                                        __ATOMIC_RELAXED,
                                        __HIP_MEMORY_SCOPE_AGENT);
        *(ull*)(buf + swzH(r, kx)) = v;
      }
    }
    __syncthreads();

    // ---- GEMM2 (2-way K-split across wave pairs) ----
    ffrag accB = {0.f, 0.f, 0.f, 0.f};
#pragma unroll 8
    for (int kk = 0; kk < 32; ++kk) {
      const int k0 = (kh << 10) + (kk << 5) + (quad << 3);
      const bfrag a = *(const bfrag*)(buf + swzH(l16, k0));
      const bfrag bm = *(const bfrag*)(g_W2b + (size_t)(zc0 + l16) * HD + k0);
      accB = __builtin_amdgcn_mfma_f32_16x16x32_bf16(a, bm, accB, 0, 0, 0);
    }
    __syncthreads();  // all buf reads done
    if (kh == 1) *(ffrag*)(red + (((nq << 6) + lane) << 2)) = accB;
    __syncthreads();
    if (kh == 0) {
      accB += *(const ffrag*)(red + (((nq << 6) + lane) << 2));
      const int zc = zc0 + l16;
      const float b2v = b2[zc];
#pragma unroll
      for (int rg = 0; rg < 4; ++rg) {
        const int row = (quad << 2) + rg;
        zreg[rg] += dtv * (accB[rg] + b2v);
        out[(size_t)(r0 + row) * ZT + (size_t)zc * TT + t + 1] = zreg[rg];
        zloc[row * 68 + (nq << 4) + l16] = f2bf(zreg[rg]);
      }
    }
    __syncthreads();

    // ---- publish z(t+1) slice (16x64) as 8B chunks ----
    if (tid < 256) {
      const int row = tid >> 4, ch = (tid & 15) << 2;
      const ull v = *(const ull*)(zloc + row * 68 + ch);
      ull* const p = &g_zbx[((r0 + row) * ZD + (ng << 6) + ch) >> 2];
      if (fast) *(volatile ull*)p = v;
      else __hip_atomic_store(p, v, __ATOMIC_RELAXED, __HIP_MEMORY_SCOPE_AGENT);
    }
    __syncthreads();  // vmcnt(0): z(t+1) at coherence point
    if (tid == 0) {
      if (fast) *(volatile unsigned*)&g_zfl[myslot] = (unsigned)(t + 2);
      else __hip_atomic_store(&g_zfl[myslot], (unsigned)(t + 2),
                              __ATOMIC_RELAXED, __HIP_MEMORY_SCOPE_AGENT);
    }
  }
}

extern "C" void kernel_launch(void* const* d_in, const int* in_sizes, int n_in,
                              void* d_out, int out_size, void* d_ws, size_t ws_size,
                              hipStream_t stream) {
  const float* z0 = (const float*)d_in[0];
  const float* ts = (const float*)d_in[1];
  const float* W1 = (const float*)d_in[2];
  const float* wt = (const float*)d_in[3];
  const float* b1 = (const float*)d_in[4];
  const float* W2 = (const float*)d_in[5];
  const float* b2 = (const float*)d_in[6];
  float* out = (float*)d_out;

  zero_flags_kernel<<<256, 64, 0, stream>>>();
  cvt_weights_kernel<<<(HD * ZD) / 1024, 256, 0, stream>>>(W1, W2);
  ode_main<<<256, 512, 0, stream>>>(z0, ts, wt, b1, b2, out);
}

// Round 6
// 2858.661 us; speedup vs baseline: 41.6199x; 41.6199x over previous
//
#include <hip/hip_runtime.h>
#include <hip/hip_bf16.h>

// NeuralODE: B=256, Z=1024, H=2048, T=128, explicit Euler, 127 steps.
// Round 10: fix the fast-path rendezvous for real.
//  R8/R9 forensics: dur scaled with the poll guard (17ms@512 -> 119ms@4096),
//  so fast polls NEVER succeeded -- sc0 loads do not bypass L1 on gfx950,
//  and a tight poll loop keeps the flag line L1-resident forever. (Data
//  staging still worked because ~512KB/step of weight streaming flushes the
//  32KB L1 between exchange-line touches.)
//  - Fast polls are now inline-asm global_atomic_add(+0, sc0=return-old):
//    atomics execute AT the L2 -- architecturally immune to L1 staleness,
//    and the shared XCD L2 is exactly where same-XCD plain publishes land.
//    (HIP fetch_add(0) is unusable: InstCombine turns idempotent RMW into an
//    atomic LOAD, reintroducing the hazard.)
//  - Publishes + flag stores (fast): plain stores (R8/R9-proven data path),
//    drained by __syncthreads' vmcnt(0).
//  - Staging (fast): sc0 loads (eviction-validated in R7/R8/R9).
//  - Stale flags across graph replays: each block sc1-zeroes ITS OWN flag
//    slots at entry, drains, THEN publishes its XCD id; any consumer poll
//    causally follows the zero under any mapping, fast or slow.
//  - Slow path (mapping check fails): bit-exact R4 sc1 protocol.
//  - Polls bounded (1024): failure -> ~35ms signature, never a hang.

#define ZD 1024
#define HD 2048
#define TT 128
#define BB 256
#define ZT (ZD * TT)
#define POLL_GUARD 1024
#define HSK_GUARD 4096

typedef __attribute__((ext_vector_type(8))) short bfrag;  // 8 bf16
typedef __attribute__((ext_vector_type(4))) float ffrag;  // 4 fp32
typedef unsigned long long ull;

__device__ short g_W1b[HD * ZD];       // 4 MB bf16, [h][z]
__device__ short g_W2b[ZD * HD];       // 4 MB bf16, [z][h]
__device__ ull g_zbx[BB * ZD / 4];     // bf16 z exchange, 8B chunks
__device__ ull g_hbx[BB * HD / 4];     // bf16 h exchange, 8B chunks
__device__ unsigned g_zfl[16 * 16 * 32];  // per-(mg,ng) z flag, 128B padded
__device__ unsigned g_hfl[16 * 16 * 32];  // per-(mg,ng) h flag, 128B padded
__device__ unsigned g_xcc[BB];            // per-block physical XCD id

__device__ __forceinline__ short f2bf(float f) {
  union { float f; unsigned u; } x; x.f = f;
  unsigned r = x.u + 0x7fffu + ((x.u >> 16) & 1u);  // RNE
  return (short)(r >> 16);
}

// XOR-swizzle of 16B blocks within an LDS row (kills stride bank conflicts).
__device__ __forceinline__ int swzA(int row, int k) {  // 1024-wide rows
  return (row << 10) + ((((k >> 3) ^ row) << 3) | (k & 7));
}
__device__ __forceinline__ int swzH(int row, int k) {  // 2048-wide rows
  return (row << 11) + ((((k >> 3) ^ row) << 3) | (k & 7));
}

// 8B load that bypasses L1-allocation concerns via the weight-stream-evicted
// L1 and reads the (XCD-shared) L2. Proven R7/R8/R9.
__device__ __forceinline__ ull ld_sc0_b64(const ull* p) {
  ull v;
  asm volatile("global_load_dwordx2 %0, %1, off sc0" : "=v"(v) : "v"(p));
  return v;  // caller must s_waitcnt vmcnt(0) before use
}

// Flag poll: atomic add-0 with return. Executes AT the L2 -- cannot be
// served from a stale L1 line, sees same-XCD plain stores.
__device__ __forceinline__ unsigned atom_poll(unsigned* p) {
  unsigned v;
  unsigned z = 0;
  asm volatile("global_atomic_add %0, %1, %2, off sc0\n\ts_waitcnt vmcnt(0)"
               : "=v"(v) : "v"(p), "v"(z) : "memory");
  return v;
}

__global__ void init_xcc_kernel() {
  const int i = threadIdx.x;
  if (i < BB)
    __hip_atomic_store(&g_xcc[i], 0xFFFFFFFFu, __ATOMIC_RELAXED,
                       __HIP_MEMORY_SCOPE_AGENT);
}

__global__ void cvt_weights_kernel(const float* __restrict__ W1,
                                   const float* __restrict__ W2) {
  const int i = (blockIdx.x * 256 + threadIdx.x) << 2;
  {
    const float4 v = *(const float4*)(W1 + i);
    short4 o; o.x = f2bf(v.x); o.y = f2bf(v.y); o.z = f2bf(v.z); o.w = f2bf(v.w);
    *(short4*)(g_W1b + i) = o;
  }
  {
    const float4 v = *(const float4*)(W2 + i);
    short4 o; o.x = f2bf(v.x); o.y = f2bf(v.y); o.z = f2bf(v.z); o.w = f2bf(v.w);
    *(short4*)(g_W2b + i) = o;
  }
}

__global__ __launch_bounds__(512, 2) void ode_main(
    const float* __restrict__ z0, const float* __restrict__ ts,
    const float* __restrict__ wt, const float* __restrict__ b1,
    const float* __restrict__ b2, float* __restrict__ out) {
  __shared__ short buf[32 * 1024];        // 64 KB, time-shared
  short* const hloc = buf + 16384;        // 16 rows x stride 132 (after GEMM1)
  short* const zloc = buf + 8192;         // 16 rows x stride 68 (after GEMM2)
  float* const red = (float*)buf;         // 4 KB K-split reduction (after GEMM2)

  const int tid = threadIdx.x;
  const int wv = tid >> 6, lane = tid & 63, l16 = lane & 15, quad = lane >> 4;
  const int b = blockIdx.x;
  // XCD-local grouping: members of a row-group share bid&7 -> same XCD
  // (verified below; falls back to sc1 protocol if the mapping doesn't hold).
  const int kb = b >> 3;                        // 0..31 within presumed XCD
  const int mg = ((b & 7) << 1) | (kb >> 4);    // row group, XCD-local
  const int ng = kb & 15;                       // column slice within group
  const int r0 = mg << 4;
  const int nq = wv & 3, kh = wv >> 2;
  const int zc0 = (ng << 6) + (nq << 4);
  const int myslot = ((mg << 4) + ng) << 5;        // my padded flag index
  const int pollslot = ((mg << 4) + l16) << 5;     // wave-0 poll index

  // ---- self-zero own flag slots (stale-replay protection, any mapping) ----
  if (tid == 0) {
    __hip_atomic_store(&g_zfl[myslot], 0u, __ATOMIC_RELAXED,
                       __HIP_MEMORY_SCOPE_AGENT);
    __hip_atomic_store(&g_hfl[myslot], 0u, __ATOMIC_RELAXED,
                       __HIP_MEMORY_SCOPE_AGENT);
    asm volatile("s_waitcnt vmcnt(0)" ::: "memory");  // zeros visible BEFORE
  }                                                   // my xcc publish below

  // ---- XCD identity handshake: decide fast (L2-local) vs slow (sc1) ----
  __shared__ unsigned s_x[24];
  __shared__ int s_fastsh;
  {
    const unsigned xcc = (unsigned)__builtin_amdgcn_s_getreg(6164) & 7u;
    // 6164 = hwreg(id=20 /*HW_REG_XCC_ID*/, offset=0, size=4)
    if (tid == 0)
      __hip_atomic_store(&g_xcc[b], xcc, __ATOMIC_RELAXED,
                         __HIP_MEMORY_SCOPE_AGENT);
    if (wv == 0) {
      int src = 0;
      if (lane < 16) {
        // bid of member `lane` of my group
        src = (mg >> 1) + ((((mg & 1) << 4) + lane) << 3);
      } else if (lane < 24) {
        src = lane - 16;  // first octet, for distinctness sanity check
      }
      unsigned v = 0xFFFFFFFFu;
      int guard = 0;
      while (true) {
        if (lane < 24 && v == 0xFFFFFFFFu)
          v = __hip_atomic_load(&g_xcc[src], __ATOMIC_RELAXED,
                                __HIP_MEMORY_SCOPE_AGENT);
        if (__all(lane >= 24 || v != 0xFFFFFFFFu)) break;
        if (++guard > HSK_GUARD) break;  // -> slow path
        __builtin_amdgcn_s_sleep(2);
      }
      if (lane < 24) s_x[lane] = v;
    }
    __syncthreads();
    if (tid == 0) {
      int ok = 1;
      const unsigned v0 = s_x[0];
      ok &= (v0 != 0xFFFFFFFFu);
      for (int j = 1; j < 16; ++j) ok &= (s_x[j] == v0);   // group co-located
      unsigned msk = 0;
      for (int j = 16; j < 24; ++j) msk |= 1u << (s_x[j] & 7u);
      ok &= (msk == 0xFFu);  // 8 distinct XCDs in first octet (hwreg sanity)
      s_fastsh = ok;
    }
    __syncthreads();
  }
  const int fast = s_fastsh;

  float zreg[4];  // fp32 z state, valid in kh==0 waves

  // ---- init: z0 -> registers, out[t=0], publish bf16 z(0) ----
  if (kh == 0) {
#pragma unroll
    for (int rg = 0; rg < 4; ++rg) {
      const int row = (quad << 2) + rg;
      zreg[rg] = z0[(r0 + row) * ZD + zc0 + l16];
      out[(size_t)(r0 + row) * ZT + (size_t)(zc0 + l16) * TT] = zreg[rg];
      zloc[row * 68 + (nq << 4) + l16] = f2bf(zreg[rg]);
    }
  }
  __syncthreads();
  if (tid < 256) {
    const int row = tid >> 4, ch = (tid & 15) << 2;
    const ull v = *(const ull*)(zloc + row * 68 + ch);
    ull* const p = &g_zbx[((r0 + row) * ZD + (ng << 6) + ch) >> 2];
    if (fast) *(volatile ull*)p = v;
    else __hip_atomic_store(p, v, __ATOMIC_RELAXED, __HIP_MEMORY_SCOPE_AGENT);
  }
  __syncthreads();  // vmcnt(0): z(0) at coherence point (XCD L2 if fast)
  if (tid == 0) {
    if (fast) *(volatile unsigned*)&g_zfl[myslot] = 1u;
    else __hip_atomic_store(&g_zfl[myslot], 1u, __ATOMIC_RELAXED,
                            __HIP_MEMORY_SCOPE_AGENT);
  }

#pragma unroll 1
  for (int t = 0; t < TT - 1; ++t) {
    const float tv = ts[t];
    const float dtv = ts[t + 1] - tv;

    // ---- wait: z(t) published by all 16 group members ----
    if (wv == 0) {
      const unsigned tgt = (unsigned)(t + 1);
      int guard = 0;
      if (fast) {
        while (true) {
          unsigned f = 0xFFFFFFFFu;
          if (lane < 16) f = atom_poll(&g_zfl[pollslot]);
          if (__all(f >= tgt)) break;      // monotone flags: >= self-heals
          if (++guard > POLL_GUARD) break; // hang-proof
          __builtin_amdgcn_s_sleep(1);
        }
      } else {
        while (true) {
          const unsigned f = __hip_atomic_load(
              &g_zfl[pollslot], __ATOMIC_RELAXED, __HIP_MEMORY_SCOPE_AGENT);
          if (__all(f >= tgt)) break;
          if (++guard > POLL_GUARD) break;
          __builtin_amdgcn_s_sleep(2);
        }
      }
    }
    __syncthreads();

    // ---- stage z (16x1024 bf16) into LDS, swizzled ----
    if (fast) {
      ull vz[8];
#pragma unroll
      for (int i = 0; i < 8; ++i) {
        const int e = tid + (i << 9);
        const int r = e >> 8, kz = (e & 255) << 2;
        vz[i] = ld_sc0_b64(&g_zbx[((r0 + r) * ZD + kz) >> 2]);
      }
      asm volatile("s_waitcnt vmcnt(0)" ::: "memory");
#pragma unroll
      for (int i = 0; i < 8; ++i) {
        const int e = tid + (i << 9);
        const int r = e >> 8, kz = (e & 255) << 2;
        *(ull*)(buf + swzA(r, kz)) = vz[i];
      }
    } else {
#pragma unroll
      for (int i = 0; i < 8; ++i) {
        const int e = tid + (i << 9);
        const int r = e >> 8, kz = (e & 255) << 2;
        const ull v = __hip_atomic_load(&g_zbx[((r0 + r) * ZD + kz) >> 2],
                                        __ATOMIC_RELAXED,
                                        __HIP_MEMORY_SCOPE_AGENT);
        *(ull*)(buf + swzA(r, kz)) = v;
      }
    }
    __syncthreads();

    // ---- GEMM1: h rows [r0,+16) cols [hc0,+16), K=1024 ----
    const int hc0 = (ng << 7) + (wv << 4);
    ffrag accA = {0.f, 0.f, 0.f, 0.f};
#pragma unroll 8
    for (int kk = 0; kk < 32; ++kk) {
      const int k0 = (kk << 5) + (quad << 3);
      const bfrag a = *(const bfrag*)(buf + swzA(l16, k0));
      const bfrag bm = *(const bfrag*)(g_W1b + (size_t)(hc0 + l16) * ZD + k0);
      accA = __builtin_amdgcn_mfma_f32_16x16x32_bf16(a, bm, accA, 0, 0, 0);
    }
    {
      const int hc = hc0 + l16;
      const float wtv = wt[hc], b1v = b1[hc];
      const int cl = (wv << 4) + l16;
#pragma unroll
      for (int rg = 0; rg < 4; ++rg)
        hloc[((quad << 2) + rg) * 132 + cl] =
            f2bf(tanhf(accA[rg] + tv * wtv + b1v));
    }
    __syncthreads();

    // ---- publish h slice (16x128) as 8B chunks ----
    {
      const int row = tid >> 5, ch = (tid & 31) << 2;
      const ull v = *(const ull*)(hloc + row * 132 + ch);
      ull* const p = &g_hbx[((r0 + row) * HD + (ng << 7) + ch) >> 2];
      if (fast) *(volatile ull*)p = v;
      else __hip_atomic_store(p, v, __ATOMIC_RELAXED, __HIP_MEMORY_SCOPE_AGENT);
    }
    __syncthreads();  // vmcnt(0): h(t) at coherence point
    if (tid == 0) {
      if (fast) *(volatile unsigned*)&g_hfl[myslot] = (unsigned)(t + 1);
      else __hip_atomic_store(&g_hfl[myslot], (unsigned)(t + 1),
                              __ATOMIC_RELAXED, __HIP_MEMORY_SCOPE_AGENT);
    }

    // ---- wait: h(t) published by all 16 group members ----
    if (wv == 0) {
      const unsigned tgt = (unsigned)(t + 1);
      int guard = 0;
      if (fast) {
        while (true) {
          unsigned f = 0xFFFFFFFFu;
          if (lane < 16) f = atom_poll(&g_hfl[pollslot]);
          if (__all(f >= tgt)) break;
          if (++guard > POLL_GUARD) break;
          __builtin_amdgcn_s_sleep(1);
        }
      } else {
        while (true) {
          const unsigned f = __hip_atomic_load(
              &g_hfl[pollslot], __ATOMIC_RELAXED, __HIP_MEMORY_SCOPE_AGENT);
          if (__all(f >= tgt)) break;
          if (++guard > POLL_GUARD) break;
          __builtin_amdgcn_s_sleep(2);
        }
      }
    }
    __syncthreads();

    // ---- stage h (16x2048 bf16 = 64 KB) into LDS, swizzled ----
    if (fast) {
      ull vh[16];
#pragma unroll
      for (int i = 0; i < 16; ++i) {
        const int e = tid + (i << 9);
        const int r = e >> 9, kx = (e & 511) << 2;
        vh[i] = ld_sc0_b64(&g_hbx[((r0 + r) * HD + kx) >> 2]);
      }
      asm volatile("s_waitcnt vmcnt(0)" ::: "memory");
#pragma unroll
      for (int i = 0; i < 16; ++i) {
        const int e = tid + (i << 9);
        const int r = e >> 9, kx = (e & 511) << 2;
        *(ull*)(buf + swzH(r, kx)) = vh[i];
      }
    } else {
#pragma unroll
      for (int i = 0; i < 16; ++i) {
        const int e = tid + (i << 9);
        const int r = e >> 9, kx = (e & 511) << 2;
        const ull v = __hip_atomic_load(&g_hbx[((r0 + r) * HD + kx) >> 2],
                                        __ATOMIC_RELAXED,
                                        __HIP_MEMORY_SCOPE_AGENT);
        *(ull*)(buf + swzH(r, kx)) = v;
      }
    }
    __syncthreads();

    // ---- GEMM2 (2-way K-split across wave pairs) ----
    ffrag accB = {0.f, 0.f, 0.f, 0.f};
#pragma unroll 8
    for (int kk = 0; kk < 32; ++kk) {
      const int k0 = (kh << 10) + (kk << 5) + (quad << 3);
      const bfrag a = *(const bfrag*)(buf + swzH(l16, k0));
      const bfrag bm = *(const bfrag*)(g_W2b + (size_t)(zc0 + l16) * HD + k0);
      accB = __builtin_amdgcn_mfma_f32_16x16x32_bf16(a, bm, accB, 0, 0, 0);
    }
    __syncthreads();  // all buf reads done
    if (kh == 1) *(ffrag*)(red + (((nq << 6) + lane) << 2)) = accB;
    __syncthreads();
    if (kh == 0) {
      accB += *(const ffrag*)(red + (((nq << 6) + lane) << 2));
      const int zc = zc0 + l16;
      const float b2v = b2[zc];
#pragma unroll
      for (int rg = 0; rg < 4; ++rg) {
        const int row = (quad << 2) + rg;
        zreg[rg] += dtv * (accB[rg] + b2v);
        out[(size_t)(r0 + row) * ZT + (size_t)zc * TT + t + 1] = zreg[rg];
        zloc[row * 68 + (nq << 4) + l16] = f2bf(zreg[rg]);
      }
    }
    __syncthreads();

    // ---- publish z(t+1) slice (16x64) as 8B chunks ----
    if (tid < 256) {
      const int row = tid >> 4, ch = (tid & 15) << 2;
      const ull v = *(const ull*)(zloc + row * 68 + ch);
      ull* const p = &g_zbx[((r0 + row) * ZD + (ng << 6) + ch) >> 2];
      if (fast) *(volatile ull*)p = v;
      else __hip_atomic_store(p, v, __ATOMIC_RELAXED, __HIP_MEMORY_SCOPE_AGENT);
    }
    __syncthreads();  // vmcnt(0): z(t+1) at coherence point
    if (tid == 0) {
      if (fast) *(volatile unsigned*)&g_zfl[myslot] = (unsigned)(t + 2);
      else __hip_atomic_store(&g_zfl[myslot], (unsigned)(t + 2),
                              __ATOMIC_RELAXED, __HIP_MEMORY_SCOPE_AGENT);
    }
  }
}

extern "C" void kernel_launch(void* const* d_in, const int* in_sizes, int n_in,
                              void* d_out, int out_size, void* d_ws, size_t ws_size,
                              hipStream_t stream) {
  const float* z0 = (const float*)d_in[0];
  const float* ts = (const float*)d_in[1];
  const float* W1 = (const float*)d_in[2];
  const float* wt = (const float*)d_in[3];
  const float* b1 = (const float*)d_in[4];
  const float* W2 = (const float*)d_in[5];
  const float* b2 = (const float*)d_in[6];
  float* out = (float*)d_out;

  init_xcc_kernel<<<1, 256, 0, stream>>>();
  cvt_weights_kernel<<<(HD * ZD) / 1024, 256, 0, stream>>>(W1, W2);
  ode_main<<<256, 512, 0, stream>>>(z0, ts, wt, b1, b2, out);
}